// Round 4
// baseline (818.619 us; speedup 1.0000x reference)
//
#include <hip/hip_runtime.h>

#define NN 8192
#define CIN 256
#define COUT 128
#define WCAP 2048
#define GR 16
#define GKT 64

__device__ __forceinline__ float lrelu_exp(float t) {
    return __expf(t >= 0.0f ? t : 0.2f * t);
}

// ---------------- Kernel A: h = x @ W (fp32) + fused a_src/a_dst ----------
// 16 rows/block, 512 blocks (2/CU), 256 threads, thread tile 2x4, K-tiled 64.
// Also zero-inits denom[8192]+cnt[256] (blocks 0..32) for the scan kernel.
__global__ __launch_bounds__(256) void gemm_h(const float* __restrict__ x,
                                              const float* __restrict__ W,
                                              const float* __restrict__ att_src,
                                              const float* __restrict__ att_dst,
                                              float* __restrict__ h,
                                              float* __restrict__ a_src,
                                              float* __restrict__ a_dst,
                                              unsigned int* __restrict__ zbuf) {
    __shared__ float Wt[GKT * COUT];      // 32 KB
    __shared__ float xt[GKT][GR + 2];     // 4.5 KB
    int tid = threadIdx.x;
    if (blockIdx.x < 33) zbuf[blockIdx.x * 256 + tid] = 0u;   // denom+cnt = 8448 words
    int i0 = blockIdx.x * GR;
    int tx = tid & 31, ty = tid >> 5;
    int c0 = tx * 4, r0 = ty * 2;
    int xr = tid >> 4, xk = (tid & 15) * 4;
    float acc[2][4] = {};

    for (int kt = 0; kt < CIN; kt += GKT) {
        float4 wv[8];
        #pragma unroll
        for (int j = 0; j < 8; ++j) {
            int f = j * 256 + tid;
            wv[j] = *(const float4*)&W[(size_t)(kt + (f >> 5)) * COUT + (f & 31) * 4];
        }
        float4 xv = *(const float4*)&x[(size_t)(i0 + xr) * CIN + kt + xk];
        __syncthreads();
        #pragma unroll
        for (int j = 0; j < 8; ++j)
            *(float4*)&Wt[(j * 256 + tid) * 4] = wv[j];
        xt[xk + 0][xr] = xv.x;
        xt[xk + 1][xr] = xv.y;
        xt[xk + 2][xr] = xv.z;
        xt[xk + 3][xr] = xv.w;
        __syncthreads();
        #pragma unroll 8
        for (int k = 0; k < GKT; ++k) {
            float4 wk = *(const float4*)&Wt[k * COUT + c0];
            float2 xf = *(const float2*)&xt[k][r0];
            acc[0][0] += xf.x * wk.x; acc[0][1] += xf.x * wk.y;
            acc[0][2] += xf.x * wk.z; acc[0][3] += xf.x * wk.w;
            acc[1][0] += xf.y * wk.x; acc[1][1] += xf.y * wk.y;
            acc[1][2] += xf.y * wk.z; acc[1][3] += xf.y * wk.w;
        }
    }

    float4 asv = *(const float4*)&att_src[c0];
    float4 adv = *(const float4*)&att_dst[c0];
    #pragma unroll
    for (int a = 0; a < 2; ++a) {
        float4 o = make_float4(acc[a][0], acc[a][1], acc[a][2], acc[a][3]);
        *(float4*)&h[(size_t)(i0 + r0 + a) * COUT + c0] = o;
        float s = o.x * asv.x + o.y * asv.y + o.z * asv.z + o.w * asv.w;
        float d = o.x * adv.x + o.y * adv.y + o.z * adv.z + o.w * adv.w;
        #pragma unroll
        for (int m = 16; m >= 1; m >>= 1) {
            s += __shfl_xor(s, m, 32);
            d += __shfl_xor(d, m, 32);
        }
        if (tx == 0) {
            a_src[i0 + r0 + a] = s;
            a_dst[i0 + r0 + a] = d;
        }
    }
}

// ---------------- Kernel B: contiguous row-major scan -> bucket scatter ----
// Block g reads 4 full adj rows ([g*4, g*4+4) x 8192) = 128 KB CONTIGUOUS
// (R3's 32 KB-strided column walk aliased to a few HBM/L2 channels ->
// 3.3 GB/s per block; sequential streaming engages all channels).
// Nonzero (i,j): w = exp(lrelu(a_src[i]+a_dst[j])); scatter (i<<5|j&31, w)
// into bucket j>>5 via global atomic counter; denom[j] += w (global atomic).
// a_dst staged whole in LDS so the divergent body is LDS/VALU-only.
// Diagonal skipped (forced self-loop added once in pass 2).
__global__ __launch_bounds__(256) void gat_scan(const unsigned int* __restrict__ adj,
                                                const float* __restrict__ a_src,
                                                const float* __restrict__ a_dst,
                                                float* __restrict__ denom,
                                                unsigned int* __restrict__ cnt,
                                                uint2* __restrict__ wl) {
    __shared__ float adstS[NN];   // 32 KB
    __shared__ float asrcS4[4];
    int tid = threadIdx.x;
    int g = blockIdx.x;
    {
        float4* dst = (float4*)adstS;
        const float4* src = (const float4*)a_dst;
        #pragma unroll
        for (int q = 0; q < 8; ++q) dst[q * 256 + tid] = src[q * 256 + tid];
    }
    if (tid < 4) asrcS4[tid] = a_src[g * 4 + tid];
    __syncthreads();

    const uint4* base = (const uint4*)adj + (size_t)g * 8192;  // 4 rows x 2048 uint4
    #pragma unroll 1
    for (int it = 0; it < 4; ++it) {
        uint4 v[8];
        #pragma unroll
        for (int b = 0; b < 8; ++b)
            v[b] = base[it * 2048 + b * 256 + tid];
        #pragma unroll
        for (int b = 0; b < 8; ++b) {
            if (v[b].x | v[b].y | v[b].z | v[b].w) {
                int f = it * 2048 + b * 256 + tid;       // uint4 idx in block
                int r = f >> 11;                         // local row 0..3
                int i = g * 4 + r;
                int c0l = (f & 2047) * 4;
                float si = asrcS4[r];
                unsigned int vv[4] = {v[b].x, v[b].y, v[b].z, v[b].w};
                #pragma unroll
                for (int q = 0; q < 4; ++q) {
                    if (vv[q] != 0u) {
                        int j = c0l + q;
                        if (i != j) {                    // diag handled in pass 2
                            float w = __uint_as_float(vv[q]) *
                                      lrelu_exp(si + adstS[j]);
                            int bkt = j >> 5;
                            unsigned int pos = atomicAdd(&cnt[bkt], 1u);
                            if (pos < WCAP)
                                wl[(size_t)bkt * WCAP + pos] =
                                    make_uint2(((unsigned)i << 5) | (unsigned)(j & 31),
                                               __float_as_uint(w));
                            atomicAdd(&denom[j], w);
                        }
                    }
                }
            }
        }
    }
}

// ---------------- Kernel C: per-bucket aggregation ------------------------
// Block b owns columns [b*32, b*32+32). Streams its contiguous bucket
// (~1024 entries), accumulates acc[jl][c] += w*h[i][c] via LDS atomics
// (lane L and L+16 alias a bank 2-way -> free). Self-loop added exactly
// once; denominator = global denom + self weight.
__global__ __launch_bounds__(1024) void gat_agg2(const float* __restrict__ h,
                                                 const float* __restrict__ a_src,
                                                 const float* __restrict__ a_dst,
                                                 const float* __restrict__ denom,
                                                 const unsigned int* __restrict__ cnt,
                                                 const uint2* __restrict__ wl,
                                                 const float* __restrict__ bias,
                                                 float* __restrict__ out) {
    __shared__ float accS[32 * COUT];   // 16 KB
    int tid = threadIdx.x;
    int j0 = blockIdx.x * 32;
    for (int t = tid; t < 32 * COUT; t += 1024) accS[t] = 0.0f;
    __syncthreads();

    int wave = tid >> 6, lane = tid & 63;
    // forced self-loops: waves 0..15 cover jl = wave, wave+16
    for (int jl = wave; jl < 32; jl += 16) {
        int j = j0 + jl;
        float w = lrelu_exp(a_src[j] + a_dst[j]);
        float2 hv = *(const float2*)&h[(size_t)j * COUT + lane * 2];
        atomicAdd(&accS[jl * COUT + lane * 2],     w * hv.x);
        atomicAdd(&accS[jl * COUT + lane * 2 + 1], w * hv.y);
    }

    int cb = (int)cnt[blockIdx.x];
    if (cb > WCAP) cb = WCAP;
    const uint2* wlb = wl + (size_t)blockIdx.x * WCAP;
    for (int e0 = wave * 4; e0 < cb; e0 += 64) {
        int n = cb - e0; if (n > 4) n = 4;
        uint2 d[4]; float2 hv[4];
        #pragma unroll
        for (int t = 0; t < 4; ++t) if (t < n) d[t] = wlb[e0 + t];
        #pragma unroll
        for (int t = 0; t < 4; ++t) if (t < n)
            hv[t] = *(const float2*)&h[(size_t)(d[t].x >> 5) * COUT + lane * 2];
        #pragma unroll
        for (int t = 0; t < 4; ++t) if (t < n) {
            int jl = (int)(d[t].x & 31u);
            float w = __uint_as_float(d[t].y);
            atomicAdd(&accS[jl * COUT + lane * 2],     w * hv[t].x);
            atomicAdd(&accS[jl * COUT + lane * 2 + 1], w * hv[t].y);
        }
    }
    __syncthreads();

    // epilogue: one float4 per thread (32 rows x 32 float4s)
    int jl = tid >> 5;
    int c = (tid & 31) * 4;
    int j = j0 + jl;
    float dtot = denom[j] + lrelu_exp(a_src[j] + a_dst[j]);
    float inv = 1.0f / dtot;
    float4 a = *(const float4*)&accS[jl * COUT + c];
    float4 b = *(const float4*)&bias[c];
    float4 o = make_float4(a.x * inv + b.x, a.y * inv + b.y,
                           a.z * inv + b.z, a.w * inv + b.w);
    *(float4*)&out[(size_t)j * COUT + c] = o;
}

extern "C" void kernel_launch(void* const* d_in, const int* in_sizes, int n_in,
                              void* d_out, int out_size, void* d_ws, size_t ws_size,
                              hipStream_t stream) {
    const float* x       = (const float*)d_in[0];
    const float* adj     = (const float*)d_in[1];
    const float* W       = (const float*)d_in[2];
    const float* att_src = (const float*)d_in[3];
    const float* att_dst = (const float*)d_in[4];
    const float* bias    = (const float*)d_in[5];
    float* out = (float*)d_out;

    float* h     = (float*)d_ws;                      // 4 MB
    float* a_src = h + (size_t)NN * COUT;             // 32 KB
    float* a_dst = a_src + NN;                        // 32 KB
    float* denom = a_dst + NN;                        // 32 KB
    unsigned int* cnt = (unsigned int*)(denom + NN);  // 1 KB (contiguous after denom)
    uint2* wl = (uint2*)(cnt + 256);                  // 256*2048*8 = 4 MB

    gemm_h  <<<NN / GR, 256, 0, stream>>>(x, W, att_src, att_dst, h, a_src, a_dst,
                                          (unsigned int*)denom);
    gat_scan<<<NN / 4, 256, 0, stream>>>((const unsigned int*)adj, a_src, a_dst,
                                         denom, cnt, wl);
    gat_agg2<<<NN / 32, 1024, 0, stream>>>(h, a_src, a_dst, denom, cnt, wl, bias, out);
}

// Round 5
// 420.580 us; speedup vs baseline: 1.9464x; 1.9464x over previous
//
#include <hip/hip_runtime.h>
#include <hip/hip_bf16.h>

#define NN 8192
#define CIN 256
#define COUT 128
#define GR 16
#define GKT 64
#define CH 8            // i-chunks
#define ICH (NN / CH)   // 1024 rows per chunk
#define KT 64           // i-rows per LDS tile

typedef unsigned short u16;
typedef _Float16 f16;
typedef __attribute__((ext_vector_type(8))) short short8;
typedef __attribute__((ext_vector_type(8))) _Float16 f16x8;
typedef __attribute__((ext_vector_type(16))) float f32x16;

__device__ __forceinline__ short8 pack8_bf16(const float* v) {
    union { __hip_bfloat162 b2[4]; short8 s; } u;
    #pragma unroll
    for (int q = 0; q < 4; ++q)
        u.b2[q] = __float22bfloat162_rn(make_float2(v[2 * q], v[2 * q + 1]));
    return u.s;
}

__device__ __forceinline__ void load_lds16(const float* g, float* l) {
    __builtin_amdgcn_global_load_lds(
        (const __attribute__((address_space(1))) void*)g,
        (__attribute__((address_space(3))) void*)l, 16, 0, 0);
}

// ---------------- Kernel A: h = x @ W (fp32) + fused a_src/a_dst ----------
// Unchanged R4 core (16 rows/block, 512 blocks, 2x4 thread tile, K-tiled 64).
// New epilogue: out-tile -> LDS -> bf16 TRANSPOSED h_t[c][i] (B-frag-ready:
// 8 consecutive i contiguous, 16 B aligned). fp32 h is no longer stored.
__global__ __launch_bounds__(256) void gemm_h(const float* __restrict__ x,
                                              const float* __restrict__ W,
                                              const float* __restrict__ att_src,
                                              const float* __restrict__ att_dst,
                                              u16* __restrict__ h_t,
                                              float* __restrict__ a_src,
                                              float* __restrict__ a_dst) {
    __shared__ float Wt[GKT * COUT];      // 32 KB
    __shared__ float xt[GKT][GR + 2];     // 4.5 KB
    __shared__ float ot[GR][COUT + 4];    // 8.3 KB transpose staging
    int tid = threadIdx.x;
    int i0 = blockIdx.x * GR;
    int tx = tid & 31, ty = tid >> 5;
    int c0 = tx * 4, r0 = ty * 2;
    int xr = tid >> 4, xk = (tid & 15) * 4;
    float acc[2][4] = {};

    for (int kt = 0; kt < CIN; kt += GKT) {
        float4 wv[8];
        #pragma unroll
        for (int j = 0; j < 8; ++j) {
            int f = j * 256 + tid;
            wv[j] = *(const float4*)&W[(size_t)(kt + (f >> 5)) * COUT + (f & 31) * 4];
        }
        float4 xv = *(const float4*)&x[(size_t)(i0 + xr) * CIN + kt + xk];
        __syncthreads();
        #pragma unroll
        for (int j = 0; j < 8; ++j)
            *(float4*)&Wt[(j * 256 + tid) * 4] = wv[j];
        xt[xk + 0][xr] = xv.x;
        xt[xk + 1][xr] = xv.y;
        xt[xk + 2][xr] = xv.z;
        xt[xk + 3][xr] = xv.w;
        __syncthreads();
        #pragma unroll 8
        for (int k = 0; k < GKT; ++k) {
            float4 wk = *(const float4*)&Wt[k * COUT + c0];
            float2 xf = *(const float2*)&xt[k][r0];
            acc[0][0] += xf.x * wk.x; acc[0][1] += xf.x * wk.y;
            acc[0][2] += xf.x * wk.z; acc[0][3] += xf.x * wk.w;
            acc[1][0] += xf.y * wk.x; acc[1][1] += xf.y * wk.y;
            acc[1][2] += xf.y * wk.z; acc[1][3] += xf.y * wk.w;
        }
    }

    float4 asv = *(const float4*)&att_src[c0];
    float4 adv = *(const float4*)&att_dst[c0];
    #pragma unroll
    for (int a = 0; a < 2; ++a) {
        float4 o = make_float4(acc[a][0], acc[a][1], acc[a][2], acc[a][3]);
        *(float4*)&ot[r0 + a][c0] = o;
        float s = o.x * asv.x + o.y * asv.y + o.z * asv.z + o.w * asv.w;
        float d = o.x * adv.x + o.y * adv.y + o.z * adv.z + o.w * adv.w;
        #pragma unroll
        for (int m = 16; m >= 1; m >>= 1) {
            s += __shfl_xor(s, m, 32);
            d += __shfl_xor(d, m, 32);
        }
        if (tx == 0) {
            a_src[i0 + r0 + a] = s;
            a_dst[i0 + r0 + a] = d;
        }
    }
    __syncthreads();
    // transpose-out: thread -> (c, half), 8 rows each, one 16 B bf16 store
    int c = tid >> 1, hf = tid & 1;
    float vals[8];
    #pragma unroll
    for (int q = 0; q < 8; ++q) vals[q] = ot[hf * 8 + q][c];
    short8 pk = pack8_bf16(vals);
    *(short8*)(h_t + (size_t)c * NN + i0 + hf * 8) = pk;
}

// ---------------- Kernel B: fused masked-GEMM (MFMA) ----------------------
// Block = (jb, ch): j-tile 128 (4 waves x 32 j), i-chunk 1024. Per 64-i
// sub-chunk: stage adj[ib:ib+64, j0:j0+128] fp32 to LDS via global_load_lds
// width-16 (rows lane-contiguous, unpadded [64][128]: bank = j&31 ->
// column reads for A-frags are conflict-free). A-frag computed on the fly:
// p = mask ? exp(lrelu(a_src[i]+a_dst[j])) : 0, packed bf16. B-frag = h_t
// (bf16, transposed) global loads (L2-hot, 2 MB). 4 n-tiles of 32 c.
// denom accumulated per-lane during A-build (each lane owns fixed j).
// No atomics, no divergence, no compaction.
__global__ __launch_bounds__(256) void gat_mm(const float* __restrict__ adj,
                                              const u16* __restrict__ h_t,
                                              const float* __restrict__ a_src,
                                              const float* __restrict__ a_dst,
                                              f16* __restrict__ pout,
                                              float* __restrict__ pden) {
    __shared__ float tileA[KT * COUT];   // 32 KB, [64 i][128 j]
    __shared__ float asrcS[ICH];         // 4 KB
    int tid = threadIdx.x;
    int lane = tid & 63, w = tid >> 6;
    int jb = blockIdx.x & 63, ch = blockIdx.x >> 6;
    int j0 = jb * 128;
    int i0 = ch * ICH;
    int half = lane >> 5;
    int jloc = w * 32 + (lane & 31);
    int gj = j0 + jloc;
    float dj = a_dst[gj];

    ((float4*)asrcS)[tid] = ((const float4*)(a_src + i0))[tid];

    f32x16 acc[4];
    #pragma unroll
    for (int nt = 0; nt < 4; ++nt)
        #pragma unroll
        for (int q = 0; q < 16; ++q) acc[nt][q] = 0.f;
    float dsum = 0.f;
    __syncthreads();

    for (int s = 0; s < ICH / KT; ++s) {
        int ib = i0 + s * KT;
        #pragma unroll
        for (int q = 0; q < 8; ++q) {
            int f = q * 256 + tid;
            const float* gp = adj + (size_t)(ib + (f >> 5)) * NN + j0 + (f & 31) * 4;
            load_lds16(gp, &tileA[f * 4]);
        }
        __syncthreads();   // vmcnt drain: tile resident
        #pragma unroll
        for (int kk = 0; kk < 4; ++kk) {
            int kb = kk * 16 + half * 8;     // local i base for this lane
            int gib = ib + kb;
            short8 bf[4];
            #pragma unroll
            for (int nt = 0; nt < 4; ++nt) {
                int c = nt * 32 + (lane & 31);
                bf[nt] = *(const short8*)(h_t + (size_t)c * NN + gib);
            }
            float av[8];
            #pragma unroll
            for (int e = 0; e < 8; ++e)
                av[e] = tileA[(kb + e) * COUT + jloc];
            float4 s0 = *(const float4*)&asrcS[s * KT + kb];
            float4 s1 = *(const float4*)&asrcS[s * KT + kb + 4];
            float sv[8] = {s0.x, s0.y, s0.z, s0.w, s1.x, s1.y, s1.z, s1.w};
            float pv[8];
            #pragma unroll
            for (int e = 0; e < 8; ++e) {
                float t = sv[e] + dj;
                float ev = __expf(fmaxf(t, 0.2f * t));   // lrelu: max(t, 0.2t)
                int gi = gib + e;
                pv[e] = (av[e] != 0.f || gi == gj) ? ev : 0.f;  // forced self-loop
                dsum += pv[e];
            }
            short8 af = pack8_bf16(pv);
            #pragma unroll
            for (int nt = 0; nt < 4; ++nt)
                acc[nt] = __builtin_amdgcn_mfma_f32_32x32x16_bf16(af, bf[nt],
                                                                  acc[nt], 0, 0, 0);
        }
        __syncthreads();
    }

    // partial C write (fp16): C/D layout col=lane&31, row=(r&3)+8*(r>>2)+4*half
    #pragma unroll
    for (int nt = 0; nt < 4; ++nt) {
        int c = nt * 32 + (lane & 31);
        #pragma unroll
        for (int r = 0; r < 16; ++r) {
            int row = (r & 3) + 8 * (r >> 2) + 4 * half;
            int j = j0 + w * 32 + row;
            pout[((size_t)ch * NN + j) * COUT + c] = (f16)acc[nt][r];
        }
    }
    float dall = dsum + __shfl_xor(dsum, 32, 64);  // halves cover disjoint k
    if (half == 0) pden[(size_t)ch * NN + gj] = dall;
}

// ---------------- Kernel C: reduce partials, normalize, bias --------------
__global__ __launch_bounds__(256) void gat_reduce(const f16* __restrict__ pout,
                                                  const float* __restrict__ pden,
                                                  const float* __restrict__ bias,
                                                  float* __restrict__ out) {
    int idx = blockIdx.x * 256 + threadIdx.x;
    int j = idx >> 4;
    int c8 = (idx & 15) * 8;
    f16x8 pv[CH];
    #pragma unroll
    for (int ch = 0; ch < CH; ++ch)
        pv[ch] = *(const f16x8*)(pout + ((size_t)ch * NN + j) * COUT + c8);
    float den = 0.f;
    #pragma unroll
    for (int ch = 0; ch < CH; ++ch) den += pden[(size_t)ch * NN + j];
    float s[8] = {};
    #pragma unroll
    for (int ch = 0; ch < CH; ++ch)
        #pragma unroll
        for (int q = 0; q < 8; ++q) s[q] += (float)pv[ch][q];
    float inv = 1.0f / den;
    float4 b0 = *(const float4*)&bias[c8];
    float4 b1 = *(const float4*)&bias[c8 + 4];
    float4 o0 = make_float4(s[0] * inv + b0.x, s[1] * inv + b0.y,
                            s[2] * inv + b0.z, s[3] * inv + b0.w);
    float4 o1 = make_float4(s[4] * inv + b1.x, s[5] * inv + b1.y,
                            s[6] * inv + b1.z, s[7] * inv + b1.w);
    *(float4*)&out[(size_t)j * COUT + c8]     = o0;
    *(float4*)&out[(size_t)j * COUT + c8 + 4] = o1;
}

extern "C" void kernel_launch(void* const* d_in, const int* in_sizes, int n_in,
                              void* d_out, int out_size, void* d_ws, size_t ws_size,
                              hipStream_t stream) {
    const float* x       = (const float*)d_in[0];
    const float* adj     = (const float*)d_in[1];
    const float* W       = (const float*)d_in[2];
    const float* att_src = (const float*)d_in[3];
    const float* att_dst = (const float*)d_in[4];
    const float* bias    = (const float*)d_in[5];
    float* out = (float*)d_out;

    u16*   h_t   = (u16*)d_ws;                                  // 2 MB
    float* a_src = (float*)((char*)d_ws + (size_t)2 * 1024 * 1024);
    float* a_dst = a_src + NN;                                  // 32 KB each
    float* pden  = a_dst + NN;                                  // 256 KB
    f16*   pout  = (f16*)(pden + (size_t)CH * NN);              // 16 MB

    gemm_h    <<<NN / GR, 256, 0, stream>>>(x, W, att_src, att_dst, h_t, a_src, a_dst);
    gat_mm    <<<64 * CH, 256, 0, stream>>>(adj, h_t, a_src, a_dst, pout, pden);
    gat_reduce<<<NN * COUT / 8 / 256, 256, 0, stream>>>(pout, pden, bias, out);
}

// Round 6
// 398.249 us; speedup vs baseline: 2.0555x; 1.0561x over previous
//
#include <hip/hip_runtime.h>
#include <hip/hip_bf16.h>

#define NN 8192
#define CIN 256
#define COUT 128
#define GR 32
#define GKT 64
#define CH 8            // i-chunks
#define ICH (NN / CH)   // 1024 rows per chunk
#define KT 64           // i-rows per LDS tile
#define HTS 72          // htS row stride in u16 (144 B: 16B-aligned, bank-balanced)

typedef unsigned short u16;
typedef _Float16 f16;
typedef __attribute__((ext_vector_type(8))) short short8;
typedef __attribute__((ext_vector_type(8))) _Float16 f16x8;
typedef __attribute__((ext_vector_type(16))) float f32x16;

__device__ __forceinline__ short8 pack8_bf16(const float* v) {
    union { __hip_bfloat162 b2[4]; short8 s; } u;
    #pragma unroll
    for (int q = 0; q < 4; ++q)
        u.b2[q] = __float22bfloat162_rn(make_float2(v[2 * q], v[2 * q + 1]));
    return u.s;
}

__device__ __forceinline__ void load_lds16(const float* g, float* l) {
    __builtin_amdgcn_global_load_lds(
        (const __attribute__((address_space(1))) void*)g,
        (__attribute__((address_space(3))) void*)l, 16, 0, 0);
}

// ---------------- Kernel A: h = x @ W (fp32) + fused a_src/a_dst ----------
// 32 rows/block, 256 blocks, 256 threads, 4x4 thread tile (R5's 2x4 was
// LDS-instr-bound: 2 LDS reads per 8 FMA at 16 waves/CU; 4x4 halves both).
// x-tile reads are same-address broadcasts (free). Epilogue: tile -> LDS ->
// bf16 transposed h_t[c][i] (B-staging-ready), + a_src/a_dst row dots.
__global__ __launch_bounds__(256) void gemm_h(const float* __restrict__ x,
                                              const float* __restrict__ W,
                                              const float* __restrict__ att_src,
                                              const float* __restrict__ att_dst,
                                              u16* __restrict__ h_t,
                                              float* __restrict__ a_src,
                                              float* __restrict__ a_dst) {
    __shared__ float Wt[GKT * COUT];      // 32 KB
    __shared__ float xt[GKT][GR + 4];     // 9 KB, transposed [k][r]
    __shared__ float ot[GR][COUT + 4];    // 16.5 KB transpose staging
    int tid = threadIdx.x;
    int i0 = blockIdx.x * GR;
    int tx = tid & 31, ty = tid >> 5;
    int c0 = tx * 4, r0 = ty * 4;
    int xr = tid >> 3, xk = (tid & 7) * 8;
    float acc[4][4] = {};

    for (int kt = 0; kt < CIN; kt += GKT) {
        float4 wv[8];
        #pragma unroll
        for (int j = 0; j < 8; ++j) {
            int f = j * 256 + tid;
            wv[j] = *(const float4*)&W[(size_t)(kt + (f >> 5)) * COUT + (f & 31) * 4];
        }
        float4 xv0 = *(const float4*)&x[(size_t)(i0 + xr) * CIN + kt + xk];
        float4 xv1 = *(const float4*)&x[(size_t)(i0 + xr) * CIN + kt + xk + 4];
        __syncthreads();
        #pragma unroll
        for (int j = 0; j < 8; ++j)
            *(float4*)&Wt[(j * 256 + tid) * 4] = wv[j];
        xt[xk + 0][xr] = xv0.x; xt[xk + 1][xr] = xv0.y;
        xt[xk + 2][xr] = xv0.z; xt[xk + 3][xr] = xv0.w;
        xt[xk + 4][xr] = xv1.x; xt[xk + 5][xr] = xv1.y;
        xt[xk + 6][xr] = xv1.z; xt[xk + 7][xr] = xv1.w;
        __syncthreads();
        #pragma unroll 8
        for (int k = 0; k < GKT; ++k) {
            float4 wk = *(const float4*)&Wt[k * COUT + c0];
            float4 xf = *(const float4*)&xt[k][r0];
            float xa[4] = {xf.x, xf.y, xf.z, xf.w};
            #pragma unroll
            for (int a = 0; a < 4; ++a) {
                acc[a][0] += xa[a] * wk.x; acc[a][1] += xa[a] * wk.y;
                acc[a][2] += xa[a] * wk.z; acc[a][3] += xa[a] * wk.w;
            }
        }
    }

    float4 asv = *(const float4*)&att_src[c0];
    float4 adv = *(const float4*)&att_dst[c0];
    #pragma unroll
    for (int a = 0; a < 4; ++a) {
        float4 o = make_float4(acc[a][0], acc[a][1], acc[a][2], acc[a][3]);
        *(float4*)&ot[r0 + a][c0] = o;
        float s = o.x * asv.x + o.y * asv.y + o.z * asv.z + o.w * asv.w;
        float d = o.x * adv.x + o.y * adv.y + o.z * adv.z + o.w * adv.w;
        #pragma unroll
        for (int m = 16; m >= 1; m >>= 1) {
            s += __shfl_xor(s, m, 32);
            d += __shfl_xor(d, m, 32);
        }
        if (tx == 0) {
            a_src[i0 + r0 + a] = s;
            a_dst[i0 + r0 + a] = d;
        }
    }
    __syncthreads();
    // transpose-out: thread -> (c, i-half of 16), two 16 B bf16 stores
    int c = tid >> 1, hf = tid & 1;
    float vals[16];
    #pragma unroll
    for (int q = 0; q < 16; ++q) vals[q] = ot[hf * 16 + q][c];
    *(short8*)(h_t + (size_t)c * NN + i0 + hf * 16)     = pack8_bf16(vals);
    *(short8*)(h_t + (size_t)c * NN + i0 + hf * 16 + 8) = pack8_bf16(vals + 8);
}

// ---------------- Kernel B: fused masked-GEMM (MFMA) ----------------------
// Block = (jb, ch): j-tile 128 (4 waves x 32 j), i-chunk 1024. Per 64-i tile:
//  - A: adj[ib:ib+64, j0:j0+128] fp32 -> LDS via global_load_lds width-16.
//  - B: h_t tile (128 c x 64 i bf16, 18 KB) -> LDS cooperatively, 128 B
//    coalesced reads; stride-72 rows (bank-balanced writes AND b128 frag
//    reads — R5 read B per-lane from global at 16 KB stride = 64-way
//    fractured transactions, ~2 GB of scattered L1 traffic: the suspect).
// A-frag on the fly: p = (adj!=0 || i==j) ? exp(lrelu(a_src+a_dst)) : 0,
// packed bf16; denom accumulated per-lane (fixed j). No atomics/divergence.
__global__ __launch_bounds__(256) void gat_mm(const float* __restrict__ adj,
                                              const u16* __restrict__ h_t,
                                              const float* __restrict__ a_src,
                                              const float* __restrict__ a_dst,
                                              f16* __restrict__ pout,
                                              float* __restrict__ pden) {
    __shared__ float tileA[KT * COUT];   // 32 KB, [64 i][128 j]
    __shared__ u16 htS[128 * HTS];       // 18 KB, [c][i] stride 72
    __shared__ float asrcS[ICH];         // 4 KB
    int tid = threadIdx.x;
    int lane = tid & 63, w = tid >> 6;
    int jb = blockIdx.x & 63, ch = blockIdx.x >> 6;
    int j0 = jb * 128;
    int i0 = ch * ICH;
    int half = lane >> 5;
    int jloc = w * 32 + (lane & 31);
    int gj = j0 + jloc;
    float dj = a_dst[gj];

    ((float4*)asrcS)[tid] = ((const float4*)(a_src + i0))[tid];

    f32x16 acc[4];
    #pragma unroll
    for (int nt = 0; nt < 4; ++nt)
        #pragma unroll
        for (int q = 0; q < 16; ++q) acc[nt][q] = 0.f;
    float dsum = 0.f;
    __syncthreads();

    for (int s = 0; s < ICH / KT; ++s) {
        int ib = i0 + s * KT;
        // A: async direct-to-LDS (rows lane-contiguous)
        #pragma unroll
        for (int q = 0; q < 8; ++q) {
            int f = q * 256 + tid;
            const float* gp = adj + (size_t)(ib + (f >> 5)) * NN + j0 + (f & 31) * 4;
            load_lds16(gp, &tileA[f * 4]);
        }
        // B: global (128 B segments per c-row) -> regs -> LDS
        short8 bv[4];
        int bc[4], bi[4];
        #pragma unroll
        for (int q = 0; q < 4; ++q) {
            int p = q * 256 + tid;
            bc[q] = p >> 3; bi[q] = (p & 7) * 8;
            bv[q] = *(const short8*)(h_t + (size_t)bc[q] * NN + ib + bi[q]);
        }
        #pragma unroll
        for (int q = 0; q < 4; ++q)
            *(short8*)(htS + bc[q] * HTS + bi[q]) = bv[q];
        __syncthreads();   // A resident (vmcnt), B visible (lgkm)

        #pragma unroll
        for (int kk = 0; kk < 4; ++kk) {
            int kb = kk * 16 + half * 8;     // local i base for this lane
            int gib = ib + kb;
            short8 bf[4];
            #pragma unroll
            for (int nt = 0; nt < 4; ++nt) {
                int c = nt * 32 + (lane & 31);
                bf[nt] = *(const short8*)(htS + c * HTS + kb);
            }
            float av[8];
            #pragma unroll
            for (int e = 0; e < 8; ++e)
                av[e] = tileA[(kb + e) * COUT + jloc];
            float4 s0 = *(const float4*)&asrcS[s * KT + kb];
            float4 s1 = *(const float4*)&asrcS[s * KT + kb + 4];
            float sv[8] = {s0.x, s0.y, s0.z, s0.w, s1.x, s1.y, s1.z, s1.w};
            float pv[8];
            #pragma unroll
            for (int e = 0; e < 8; ++e) {
                float t = sv[e] + dj;
                float ev = __expf(fmaxf(t, 0.2f * t));   // lrelu then exp
                int gi = gib + e;
                pv[e] = (av[e] != 0.f || gi == gj) ? ev : 0.f;  // forced self-loop
                dsum += pv[e];
            }
            short8 af = pack8_bf16(pv);
            #pragma unroll
            for (int nt = 0; nt < 4; ++nt)
                acc[nt] = __builtin_amdgcn_mfma_f32_32x32x16_bf16(af, bf[nt],
                                                                  acc[nt], 0, 0, 0);
        }
        __syncthreads();
    }

    // partial C write (fp16): C/D layout col=lane&31, row=(r&3)+8*(r>>2)+4*half
    #pragma unroll
    for (int nt = 0; nt < 4; ++nt) {
        int c = nt * 32 + (lane & 31);
        #pragma unroll
        for (int r = 0; r < 16; ++r) {
            int row = (r & 3) + 8 * (r >> 2) + 4 * half;
            int j = j0 + w * 32 + row;
            pout[((size_t)ch * NN + j) * COUT + c] = (f16)acc[nt][r];
        }
    }
    float dall = dsum + __shfl_xor(dsum, 32, 64);  // halves cover disjoint k
    if (half == 0) pden[(size_t)ch * NN + gj] = dall;
}

// ---------------- Kernel C: reduce partials, normalize, bias --------------
__global__ __launch_bounds__(256) void gat_reduce(const f16* __restrict__ pout,
                                                  const float* __restrict__ pden,
                                                  const float* __restrict__ bias,
                                                  float* __restrict__ out) {
    int idx = blockIdx.x * 256 + threadIdx.x;
    int j = idx >> 4;
    int c8 = (idx & 15) * 8;
    f16x8 pv[CH];
    #pragma unroll
    for (int ch = 0; ch < CH; ++ch)
        pv[ch] = *(const f16x8*)(pout + ((size_t)ch * NN + j) * COUT + c8);
    float den = 0.f;
    #pragma unroll
    for (int ch = 0; ch < CH; ++ch) den += pden[(size_t)ch * NN + j];
    float s[8] = {};
    #pragma unroll
    for (int ch = 0; ch < CH; ++ch)
        #pragma unroll
        for (int q = 0; q < 8; ++q) s[q] += (float)pv[ch][q];
    float inv = 1.0f / den;
    float4 b0 = *(const float4*)&bias[c8];
    float4 b1 = *(const float4*)&bias[c8 + 4];
    float4 o0 = make_float4(s[0] * inv + b0.x, s[1] * inv + b0.y,
                            s[2] * inv + b0.z, s[3] * inv + b0.w);
    float4 o1 = make_float4(s[4] * inv + b1.x, s[5] * inv + b1.y,
                            s[6] * inv + b1.z, s[7] * inv + b1.w);
    *(float4*)&out[(size_t)j * COUT + c8]     = o0;
    *(float4*)&out[(size_t)j * COUT + c8 + 4] = o1;
}

extern "C" void kernel_launch(void* const* d_in, const int* in_sizes, int n_in,
                              void* d_out, int out_size, void* d_ws, size_t ws_size,
                              hipStream_t stream) {
    const float* x       = (const float*)d_in[0];
    const float* adj     = (const float*)d_in[1];
    const float* W       = (const float*)d_in[2];
    const float* att_src = (const float*)d_in[3];
    const float* att_dst = (const float*)d_in[4];
    const float* bias    = (const float*)d_in[5];
    float* out = (float*)d_out;

    u16*   h_t   = (u16*)d_ws;                                  // 2 MB
    float* a_src = (float*)((char*)d_ws + (size_t)2 * 1024 * 1024);
    float* a_dst = a_src + NN;                                  // 32 KB each
    float* pden  = a_dst + NN;                                  // 256 KB
    f16*   pout  = (f16*)(pden + (size_t)CH * NN);              // 16 MB

    gemm_h    <<<NN / GR, 256, 0, stream>>>(x, W, att_src, att_dst, h_t, a_src, a_dst);
    gat_mm    <<<64 * CH, 256, 0, stream>>>(adj, h_t, a_src, a_dst, pout, pden);
    gat_reduce<<<NN * COUT / 8 / 256, 256, 0, stream>>>(pout, pden, bias, out);
}